// Round 2
// baseline (250.571 us; speedup 1.0000x reference)
//
#include <hip/hip_runtime.h>
#include <math.h>

#define D_PROJ 8192
#define C_IN   512
#define P_SP   196   // 14*14
#define NBATCH 32
#define NTILE  16    // 4x4 channel tiles of 128
#define PCH    14    // P chunk
#define NCH    7     // chunks per block (half of P: 98 = 7*14)
#define LDA    132   // padded LDS row stride (floats)

// ---------------------------------------------------------------------------
// Recover count-sketch (h, s) from the dense [512, 8192] matrices: each row
// has exactly one nonzero (value +-1) at column h[row]. Rows 0..511 -> sketch
// 1, rows 512..1023 -> sketch 2, float4 reads.
// ---------------------------------------------------------------------------
__global__ __launch_bounds__(256) void extract_sketch(
    const float* __restrict__ S1, const float* __restrict__ S2,
    int* __restrict__ h1, float* __restrict__ s1,
    int* __restrict__ h2, float* __restrict__ s2)
{
    const int row = blockIdx.x;            // 0..1023
    const int r   = row & (C_IN - 1);
    const float* S = (row < C_IN) ? S1 : S2;
    int*   h = (row < C_IN) ? h1 : h2;
    float* s = (row < C_IN) ? s1 : s2;
    const float4* rp = (const float4*)(S + (size_t)r * D_PROJ);
    for (int c = threadIdx.x; c < D_PROJ / 4; c += 256) {
        float4 v = rp[c];
        if (v.x != 0.0f) { h[r] = 4 * c;     s[r] = v.x; }
        if (v.y != 0.0f) { h[r] = 4 * c + 1; s[r] = v.y; }
        if (v.z != 0.0f) { h[r] = 4 * c + 2; s[r] = v.z; }
        if (v.w != 0.0f) { h[r] = 4 * c + 3; s[r] = v.w; }
    }
}

// ---------------------------------------------------------------------------
// Fused Gram + count-sketch-of-outer-product scatter, split-P version.
// Grid = 1024 blocks: (batch, tile 0..15, p-half 0..1), XCD-swizzled so all
// 32 blocks of a batch land on one XCD (x reads and partial slices stay in
// that XCD's L2). Each block computes a 128x128 G tile over its 98-wide P
// half (7 chunks of 14) with 8x8 register blocking, scatters
// s1[i]*s2[j]*G[i,j] into an 8192-bin LDS histogram, then flushes:
//   mode 2: private non-atomic float4 slice (1024 slices in ws)
//   mode 1: pairwise same-XCD atomics into 512 slices
//   mode 0: full fallback, atomics into d_out
// Staging is register-buffered (T14): chunk ch+1's global loads issue before
// the compute barrier so L2 latency hides under chunk ch's FMAs.
// ---------------------------------------------------------------------------
__global__ __launch_bounds__(256) void gram_scatter(
    const float* __restrict__ x,
    const int* __restrict__ h1, const float* __restrict__ s1,
    const int* __restrict__ h2, const float* __restrict__ s2,
    float* __restrict__ dest, int mode)
{
    __shared__ __align__(16) float accL[D_PROJ];         // 32 KB histogram
    __shared__ __align__(16) float As[PCH * LDA];        // 7.2 KB, p-major
    __shared__ __align__(16) float Bs[PCH * LDA];
    __shared__ int   h1L[128];
    __shared__ float s1L[128];
    __shared__ int   h2L[128];
    __shared__ float s2L[128];

    const int tid = threadIdx.x;
    const int tx  = tid & 15;        // j quad
    const int ty  = tid >> 4;        // i quad

    // XCD-aware decomposition: id%8 selects XCD slot (hw round-robin).
    const int id   = blockIdx.x;     // 0..1023
    const int xcd  = id & 7;
    const int rem  = id >> 3;        // 0..127
    const int half = rem & 1;        // p half
    const int tile = (rem >> 1) & 15;
    const int b    = xcd + 8 * (rem >> 5);
    const int it   = tile >> 2;      // i tile (0..3)
    const int jt   = tile & 3;       // j tile (0..3)

    if (tid < 128) {
        h1L[tid] = h1[it * 128 + tid];
        s1L[tid] = s1[it * 128 + tid];
        h2L[tid] = h2[jt * 128 + tid];
        s2L[tid] = s2[jt * 128 + tid];
    }
    for (int k = tid; k < D_PROJ; k += 256) accL[k] = 0.0f;

    const float* xi = x + ((size_t)b * C_IN + it * 128) * P_SP;
    const float* xj = x + ((size_t)b * C_IN + jt * 128) * P_SP;
    const int pbase = half * (NCH * PCH);    // 0 or 98 (even -> float2 aligned)

    // Per-e staging map (tid-invariant across chunks; LICM hoists the math).
    // idx = e*256+tid in [0,1792): first 896 float2 -> As from xi, rest -> Bs
    // from xj. Boundary 896 is a multiple of 64 -> wave-uniform select.
    float2 st[NCH];
#define STAGE_LOAD(CH) do {                                                   \
        const int p0_ = pbase + (CH) * PCH;                                   \
        _Pragma("unroll")                                                     \
        for (int e = 0; e < 7; ++e) {                                         \
            int idx = e * 256 + tid;                                          \
            int ar  = idx >= 896;                                             \
            int rm  = ar ? idx - 896 : idx;                                   \
            int il  = rm / 7;                                                 \
            int q   = rm - il * 7;                                            \
            const float* src = ar ? xj : xi;                                  \
            st[e] = *(const float2*)(src + il * P_SP + p0_ + 2 * q);          \
        }                                                                     \
    } while (0)

    float acc[8][8];
    #pragma unroll
    for (int r = 0; r < 8; ++r)
        #pragma unroll
        for (int c = 0; c < 8; ++c) acc[r][c] = 0.0f;

    STAGE_LOAD(0);

    for (int ch = 0; ch < NCH; ++ch) {
        __syncthreads();   // prev compute done (and hist zero / params on ch==0)
        #pragma unroll
        for (int e = 0; e < 7; ++e) {            // regs -> LDS
            int idx = e * 256 + tid;
            int ar  = idx >= 896;
            int rm  = ar ? idx - 896 : idx;
            int il  = rm / 7;
            int q   = rm - il * 7;
            float* dst = ar ? Bs : As;
            dst[(2 * q) * LDA + il]     = st[e].x;
            dst[(2 * q + 1) * LDA + il] = st[e].y;
        }
        if (ch + 1 < NCH) STAGE_LOAD(ch + 1);    // prefetch: latency hides under FMAs
        __syncthreads();
        #pragma unroll
        for (int pp = 0; pp < PCH; ++pp) {
            const float* ap = &As[pp * LDA];
            const float* bp = &Bs[pp * LDA];
            float4 a0 = *(const float4*)(ap + ty * 4);
            float4 a1 = *(const float4*)(ap + 64 + ty * 4);
            float4 b0 = *(const float4*)(bp + tx * 4);
            float4 b1 = *(const float4*)(bp + 64 + tx * 4);
            float av[8] = {a0.x, a0.y, a0.z, a0.w, a1.x, a1.y, a1.z, a1.w};
            float bv[8] = {b0.x, b0.y, b0.z, b0.w, b1.x, b1.y, b1.z, b1.w};
            #pragma unroll
            for (int r = 0; r < 8; ++r)
                #pragma unroll
                for (int c = 0; c < 8; ++c)
                    acc[r][c] = fmaf(av[r], bv[c], acc[r][c]);
        }
    }
#undef STAGE_LOAD

    // Scatter the G tile through the count-sketch into the LDS histogram.
    #pragma unroll
    for (int r = 0; r < 8; ++r) {
        int   il = (r < 4) ? (ty * 4 + r) : (64 + ty * 4 + (r - 4));
        int   hA = h1L[il];
        float sA = s1L[il];
        #pragma unroll
        for (int c = 0; c < 8; ++c) {
            int jl = (c < 4) ? (tx * 4 + c) : (64 + tx * 4 + (c - 4));
            int d  = (hA + h2L[jl]) & (D_PROJ - 1);
            atomicAdd(&accL[d], sA * s2L[jl] * acc[r][c]);
        }
    }
    __syncthreads();

    if (mode == 2) {
        // Private slice: no atomics, fully coalesced float4 stores.
        float* pb = dest + ((size_t)((b * NTILE + tile) * 2 + half)) * D_PROJ;
        for (int k = tid * 4; k < D_PROJ; k += 1024)
            *(float4*)(pb + k) = *(const float4*)(accL + k);
    } else if (mode == 1) {
        // Pairwise contention only, same XCD after swizzle.
        float* pb = dest + (size_t)(b * NTILE + tile) * D_PROJ;
        for (int k = tid; k < D_PROJ; k += 256) atomicAdd(&pb[k], accL[k]);
    } else {
        float* pb = dest + (size_t)b * D_PROJ;
        for (int k = tid; k < D_PROJ; k += 256) atomicAdd(&pb[k], accL[k]);
    }
}

// ---------------------------------------------------------------------------
// Partial-path finalize: per batch, sum the ns tile slices (t-outer loop: 8
// independent float4 loads in flight per step), then norm and signed sqrt.
// ---------------------------------------------------------------------------
__device__ inline float ssqrt_scale(float v, float inv)
{
    float r = sqrtf(fabsf(v) + 1e-8f) * inv;
    return (v > 0.0f) ? r : ((v < 0.0f) ? -r : 0.0f);
}

__global__ __launch_bounds__(256) void finalize_partial(
    const float* __restrict__ partial, float* __restrict__ out, int ns)
{
    const int b   = blockIdx.x;
    const int tid = threadIdx.x;
    const float* base = partial + (size_t)b * ns * D_PROJ;

    float4 acc[8];
    #pragma unroll
    for (int n = 0; n < 8; ++n) acc[n] = make_float4(0.f, 0.f, 0.f, 0.f);

    for (int t = 0; t < ns; ++t) {
        const float* bt = base + (size_t)t * D_PROJ;
        #pragma unroll
        for (int n = 0; n < 8; ++n) {
            float4 v = *(const float4*)(bt + tid * 4 + n * 1024);
            acc[n].x += v.x; acc[n].y += v.y; acc[n].z += v.z; acc[n].w += v.w;
        }
    }

    float s = 0.0f;
    #pragma unroll
    for (int n = 0; n < 8; ++n)
        s += fabsf(acc[n].x) + fabsf(acc[n].y) + fabsf(acc[n].z) + fabsf(acc[n].w);

    #pragma unroll
    for (int off = 32; off > 0; off >>= 1) s += __shfl_down(s, off, 64);
    __shared__ float red[4];
    if ((tid & 63) == 0) red[tid >> 6] = s;
    __syncthreads();
    float total = red[0] + red[1] + red[2] + red[3];
    float inv   = 1.0f / fmaxf(sqrtf(total + (float)D_PROJ * 1e-8f), 1e-12f);

    float* ob = out + (size_t)b * D_PROJ;
    #pragma unroll
    for (int n = 0; n < 8; ++n) {
        const int k = tid * 4 + n * 1024;
        float4 a = acc[n];
        float4 r;
        r.x = ssqrt_scale(a.x, inv);
        r.y = ssqrt_scale(a.y, inv);
        r.z = ssqrt_scale(a.z, inv);
        r.w = ssqrt_scale(a.w, inv);
        *(float4*)(ob + k) = r;
    }
}

// ---------------------------------------------------------------------------
// Atomic-path fallback finalize (in-place on d_out).
// ---------------------------------------------------------------------------
__global__ __launch_bounds__(256) void finalize_inplace(float* __restrict__ out)
{
    const int b = blockIdx.x;
    float* p = out + (size_t)b * D_PROJ;
    const int tid = threadIdx.x;

    float s = 0.0f;
    for (int d = tid; d < D_PROJ; d += 256) s += fabsf(p[d]);
    #pragma unroll
    for (int off = 32; off > 0; off >>= 1) s += __shfl_down(s, off, 64);

    __shared__ float red[4];
    if ((tid & 63) == 0) red[tid >> 6] = s;
    __syncthreads();
    float total = red[0] + red[1] + red[2] + red[3];
    float inv   = 1.0f / fmaxf(sqrtf(total + (float)D_PROJ * 1e-8f), 1e-12f);

    for (int d = tid; d < D_PROJ; d += 256) {
        float v = p[d];
        float r = sqrtf(fabsf(v) + 1e-8f) * inv;
        p[d] = (v > 0.0f) ? r : ((v < 0.0f) ? -r : 0.0f);
    }
}

// ---------------------------------------------------------------------------
extern "C" void kernel_launch(void* const* d_in, const int* in_sizes, int n_in,
                              void* d_out, int out_size, void* d_ws, size_t ws_size,
                              hipStream_t stream)
{
    const float* x  = (const float*)d_in[0];   // [32, 512, 14, 14]
    const float* S1 = (const float*)d_in[1];   // [512, 8192]
    const float* S2 = (const float*)d_in[2];   // [512, 8192]
    float* out = (float*)d_out;                // [32, 8192]

    char* ws = (char*)d_ws;
    int*   h1 = (int*)(ws);
    float* s1 = (float*)(ws + 2048);
    int*   h2 = (int*)(ws + 4096);
    float* s2 = (float*)(ws + 6144);
    float* partial = (float*)(ws + 8192);

    const size_t need2 = 8192 + (size_t)NBATCH * NTILE * 2 * D_PROJ * sizeof(float); // 33.6 MB
    const size_t need1 = 8192 + (size_t)NBATCH * NTILE * D_PROJ * sizeof(float);     // 16.8 MB

    extract_sketch<<<1024, 256, 0, stream>>>(S1, S2, h1, s1, h2, s2);

    if (ws_size >= need2) {
        gram_scatter<<<1024, 256, 0, stream>>>(x, h1, s1, h2, s2, partial, 2);
        finalize_partial<<<NBATCH, 256, 0, stream>>>(partial, out, NTILE * 2);
    } else if (ws_size >= need1) {
        hipMemsetAsync(partial, 0, (size_t)NBATCH * NTILE * D_PROJ * sizeof(float), stream);
        gram_scatter<<<1024, 256, 0, stream>>>(x, h1, s1, h2, s2, partial, 1);
        finalize_partial<<<NBATCH, 256, 0, stream>>>(partial, out, NTILE);
    } else {
        hipMemsetAsync(d_out, 0, (size_t)out_size * sizeof(float), stream);
        gram_scatter<<<1024, 256, 0, stream>>>(x, h1, s1, h2, s2, out, 0);
        finalize_inplace<<<NBATCH, 256, 0, stream>>>(out);
    }
}

// Round 3
// 208.894 us; speedup vs baseline: 1.1995x; 1.1995x over previous
//
#include <hip/hip_runtime.h>
#include <math.h>

#define D_PROJ 8192
#define C_IN   512
#define P_SP   196   // 14*14
#define NBATCH 32
#define NTILE  16    // 4x4 channel tiles of 128
#define PCH    14    // P chunk (196 = 14*14)
#define NCHUNK 14
#define LDA    132   // legacy path only

// ---------------------------------------------------------------------------
// global -> LDS direct DMA, 16B per lane. LDS dest is wave-uniform base +
// lane*16 (HW rule); global src is per-lane.
// ---------------------------------------------------------------------------
__device__ inline void gload_lds16(const float* gsrc, float* ldst)
{
    __builtin_amdgcn_global_load_lds(
        (const __attribute__((address_space(1))) void*)(gsrc),
        (__attribute__((address_space(3))) void*)(ldst),
        16, 0, 0);
}

// ---------------------------------------------------------------------------
// Recover count-sketch (h, s): each row of S has exactly one nonzero (+-1) at
// column h[row]. Rows 0..511 -> sketch 1, 512..1023 -> sketch 2.
// ---------------------------------------------------------------------------
__global__ __launch_bounds__(256) void extract_sketch(
    const float* __restrict__ S1, const float* __restrict__ S2,
    int* __restrict__ h1, float* __restrict__ s1,
    int* __restrict__ h2, float* __restrict__ s2)
{
    const int row = blockIdx.x;            // 0..1023
    const int r   = row & (C_IN - 1);
    const float* S = (row < C_IN) ? S1 : S2;
    int*   h = (row < C_IN) ? h1 : h2;
    float* s = (row < C_IN) ? s1 : s2;
    const float4* rp = (const float4*)(S + (size_t)r * D_PROJ);
    for (int c = threadIdx.x; c < D_PROJ / 4; c += 256) {
        float4 v = rp[c];
        if (v.x != 0.0f) { h[r] = 4 * c;     s[r] = v.x; }
        if (v.y != 0.0f) { h[r] = 4 * c + 1; s[r] = v.y; }
        if (v.z != 0.0f) { h[r] = 4 * c + 2; s[r] = v.z; }
        if (v.w != 0.0f) { h[r] = 4 * c + 3; s[r] = v.w; }
    }
}

// ---------------------------------------------------------------------------
// x[b][c][p] -> xT[b][p][c]. 64x64 LDS-tiled transpose, coalesced both sides.
// ---------------------------------------------------------------------------
__global__ __launch_bounds__(256) void transpose_x(
    const float* __restrict__ x, float* __restrict__ xT)
{
    __shared__ float t[64][65];
    const int b  = blockIdx.z;
    const int pt = blockIdx.x;            // p tile 0..3 (last is 4 rows)
    const int ct = blockIdx.y;            // c tile 0..7
    const int tx = threadIdx.x & 63;
    const int ty = threadIdx.x >> 6;      // 0..3
    const int p0 = pt * 64, c0 = ct * 64;
    const float* xb  = x  + (size_t)b * C_IN * P_SP;
    float*       xtb = xT + (size_t)b * P_SP * C_IN;

    #pragma unroll
    for (int k = ty; k < 64; k += 4) {
        int p = p0 + tx;
        t[k][tx] = (p < P_SP) ? xb[(size_t)(c0 + k) * P_SP + p] : 0.0f;
    }
    __syncthreads();
    #pragma unroll
    for (int k = ty; k < 64; k += 4) {
        int p = p0 + k;
        if (p < P_SP) xtb[(size_t)p * C_IN + c0 + tx] = t[tx][k];
    }
}

// ---------------------------------------------------------------------------
// Fused Gram + count-sketch scatter, DMA-staged double-buffered version.
// Grid = 512 blocks (batch x 16 tiles), XCD-swizzled (id&7 = hw round-robin
// slot) so a batch's 16 blocks share one XCD's L2 for x and partial slices.
// Per chunk: issue next chunk's global_load_lds DMA, compute current from
// LDS double buffer, ONE barrier (its implicit vmcnt(0) drains the DMA).
//   mode 1: private non-atomic float4 slice per block (512 slices in ws)
//   mode 0: atomics into d_out (fallback)
// ---------------------------------------------------------------------------
__global__ __launch_bounds__(256) void gram_scatter(
    const float* __restrict__ xT,
    const int* __restrict__ h1, const float* __restrict__ s1,
    const int* __restrict__ h2, const float* __restrict__ s2,
    float* __restrict__ dest, int mode)
{
    __shared__ __align__(16) float accL[D_PROJ];          // 32 KB histogram
    __shared__ __align__(16) float As[2][PCH][128];       // 14 KB (dbuf)
    __shared__ __align__(16) float Bs[2][PCH][128];       // 14 KB (dbuf)
    __shared__ int   h1L[128];
    __shared__ float s1L[128];
    __shared__ int   h2L[128];
    __shared__ float s2L[128];

    const int tid  = threadIdx.x;
    const int tx   = tid & 15;       // j quad
    const int ty   = tid >> 4;       // i quad
    const int wid  = tid >> 6;       // wave 0..3
    const int lane = tid & 63;

    const int id   = blockIdx.x;     // 0..511
    const int xcd  = id & 7;
    const int rem  = id >> 3;        // 0..63
    const int tile = rem & 15;
    const int b    = xcd + 8 * (rem >> 4);
    const int it   = tile >> 2;
    const int jt   = tile & 3;

    const float* xb = xT + (size_t)b * P_SP * C_IN;
    const int cbA = it * 128, cbB = jt * 128;

    // Issue the 14 DMA instrs for chunk ch into buffer bufi (wave-distributed:
    // each instr covers 2 rows of 128 floats = 1 KB; lds dest wave-uniform).
    #define ISSUE_DMA(CH, BUFI) do {                                          \
        const float* base_ = xb + (size_t)(CH) * PCH * C_IN;                  \
        for (int k = wid; k < 14; k += 4) {                                   \
            int aSel = (k < 7);                                               \
            int pr   = aSel ? 2 * k : 2 * (k - 7);                            \
            int cb_  = aSel ? cbA : cbB;                                      \
            const float* g = base_ + (size_t)(pr + (lane >> 5)) * C_IN        \
                             + cb_ + (lane & 31) * 4;                         \
            float* l = aSel ? &As[BUFI][pr][0] : &Bs[BUFI][pr][0];            \
            gload_lds16(g, l);                                                \
        }                                                                     \
    } while (0)

    ISSUE_DMA(0, 0);                               // latency hides under zeroing
    if (tid < 128) {
        h1L[tid] = h1[cbA + tid];
        s1L[tid] = s1[cbA + tid];
        h2L[tid] = h2[cbB + tid];
        s2L[tid] = s2[cbB + tid];
    }
    for (int k = tid; k < D_PROJ; k += 256) accL[k] = 0.0f;

    float acc[8][8];
    #pragma unroll
    for (int r = 0; r < 8; ++r)
        #pragma unroll
        for (int c = 0; c < 8; ++c) acc[r][c] = 0.0f;

    __syncthreads();                               // chunk 0 ready

    for (int ch = 0; ch < NCHUNK; ++ch) {
        const int cur = ch & 1;
        if (ch + 1 < NCHUNK) ISSUE_DMA(ch + 1, cur ^ 1);
        #pragma unroll
        for (int pp = 0; pp < PCH; ++pp) {
            const float* ap = &As[cur][pp][0];
            const float* bp = &Bs[cur][pp][0];
            float4 a0 = *(const float4*)(ap + ty * 4);
            float4 a1 = *(const float4*)(ap + 64 + ty * 4);
            float4 b0 = *(const float4*)(bp + tx * 4);
            float4 b1 = *(const float4*)(bp + 64 + tx * 4);
            float av[8] = {a0.x, a0.y, a0.z, a0.w, a1.x, a1.y, a1.z, a1.w};
            float bv[8] = {b0.x, b0.y, b0.z, b0.w, b1.x, b1.y, b1.z, b1.w};
            #pragma unroll
            for (int r = 0; r < 8; ++r)
                #pragma unroll
                for (int c = 0; c < 8; ++c)
                    acc[r][c] = fmaf(av[r], bv[c], acc[r][c]);
        }
        __syncthreads();   // implicit vmcnt(0)+lgkmcnt(0): next chunk ready
    }
    #undef ISSUE_DMA

    // Scatter the G tile through the count-sketch into the LDS histogram.
    #pragma unroll
    for (int r = 0; r < 8; ++r) {
        int   il = (r < 4) ? (ty * 4 + r) : (64 + ty * 4 + (r - 4));
        int   hA = h1L[il];
        float sA = s1L[il];
        #pragma unroll
        for (int c = 0; c < 8; ++c) {
            int jl = (c < 4) ? (tx * 4 + c) : (64 + tx * 4 + (c - 4));
            int d  = (hA + h2L[jl]) & (D_PROJ - 1);
            atomicAdd(&accL[d], sA * s2L[jl] * acc[r][c]);
        }
    }
    __syncthreads();

    if (mode == 1) {
        float* pb = dest + (size_t)(b * NTILE + tile) * D_PROJ;
        for (int k = tid * 4; k < D_PROJ; k += 1024)
            *(float4*)(pb + k) = *(const float4*)(accL + k);
    } else {
        float* pb = dest + (size_t)b * D_PROJ;
        for (int k = tid; k < D_PROJ; k += 256) atomicAdd(&pb[k], accL[k]);
    }
}

// ---------------------------------------------------------------------------
// Legacy gram (R1 staging, reads x directly) — only if ws is too small for xT.
// ---------------------------------------------------------------------------
__global__ __launch_bounds__(256) void gram_scatter_legacy(
    const float* __restrict__ x,
    const int* __restrict__ h1, const float* __restrict__ s1,
    const int* __restrict__ h2, const float* __restrict__ s2,
    float* __restrict__ pool)
{
    __shared__ float accL[D_PROJ];
    __shared__ __align__(16) float As[PCH * LDA];
    __shared__ __align__(16) float Bs[PCH * LDA];
    __shared__ int   h1L[128];
    __shared__ float s1L[128];
    __shared__ int   h2L[128];
    __shared__ float s2L[128];

    const int tid = threadIdx.x;
    const int tx  = tid & 15;
    const int ty  = tid >> 4;
    const int id  = blockIdx.x;
    const int xcd = id & 7;
    const int rem = id >> 3;
    const int tile = rem & 15;
    const int b   = xcd + 8 * (rem >> 4);
    const int it  = tile >> 2;
    const int jt  = tile & 3;

    if (tid < 128) {
        h1L[tid] = h1[it * 128 + tid];
        s1L[tid] = s1[it * 128 + tid];
        h2L[tid] = h2[jt * 128 + tid];
        s2L[tid] = s2[jt * 128 + tid];
    }
    for (int k = tid; k < D_PROJ; k += 256) accL[k] = 0.0f;

    const float* xi = x + ((size_t)b * C_IN + it * 128) * P_SP;
    const float* xj = x + ((size_t)b * C_IN + jt * 128) * P_SP;

    float acc[8][8];
    #pragma unroll
    for (int r = 0; r < 8; ++r)
        #pragma unroll
        for (int c = 0; c < 8; ++c) acc[r][c] = 0.0f;

    for (int ch = 0; ch < P_SP / PCH; ++ch) {
        const int p0 = ch * PCH;
        __syncthreads();
        #pragma unroll
        for (int e = 0; e < 7; ++e) {
            int idx = e * 256 + tid;
            int il  = idx / PCH;
            int pp  = idx - il * PCH;
            As[pp * LDA + il] = xi[il * P_SP + p0 + pp];
            Bs[pp * LDA + il] = xj[il * P_SP + p0 + pp];
        }
        __syncthreads();
        #pragma unroll
        for (int pp = 0; pp < PCH; ++pp) {
            const float* ap = &As[pp * LDA];
            const float* bp = &Bs[pp * LDA];
            float4 a0 = *(const float4*)(ap + ty * 4);
            float4 a1 = *(const float4*)(ap + 64 + ty * 4);
            float4 b0 = *(const float4*)(bp + tx * 4);
            float4 b1 = *(const float4*)(bp + 64 + tx * 4);
            float av[8] = {a0.x, a0.y, a0.z, a0.w, a1.x, a1.y, a1.z, a1.w};
            float bv[8] = {b0.x, b0.y, b0.z, b0.w, b1.x, b1.y, b1.z, b1.w};
            #pragma unroll
            for (int r = 0; r < 8; ++r)
                #pragma unroll
                for (int c = 0; c < 8; ++c)
                    acc[r][c] = fmaf(av[r], bv[c], acc[r][c]);
        }
    }

    #pragma unroll
    for (int r = 0; r < 8; ++r) {
        int   il = (r < 4) ? (ty * 4 + r) : (64 + ty * 4 + (r - 4));
        int   hA = h1L[il];
        float sA = s1L[il];
        #pragma unroll
        for (int c = 0; c < 8; ++c) {
            int jl = (c < 4) ? (tx * 4 + c) : (64 + tx * 4 + (c - 4));
            int d  = (hA + h2L[jl]) & (D_PROJ - 1);
            atomicAdd(&accL[d], sA * s2L[jl] * acc[r][c]);
        }
    }
    __syncthreads();

    float* pb = pool + (size_t)b * D_PROJ;
    for (int k = tid; k < D_PROJ; k += 256) atomicAdd(&pb[k], accL[k]);
}

// ---------------------------------------------------------------------------
__device__ inline float ssqrt_scale(float v, float inv)
{
    float r = sqrtf(fabsf(v) + 1e-8f) * inv;
    return (v > 0.0f) ? r : ((v < 0.0f) ? -r : 0.0f);
}

__global__ __launch_bounds__(256) void finalize_partial(
    const float* __restrict__ partial, float* __restrict__ out, int ns)
{
    const int b   = blockIdx.x;
    const int tid = threadIdx.x;
    const float* base = partial + (size_t)b * ns * D_PROJ;

    float4 acc[8];
    #pragma unroll
    for (int n = 0; n < 8; ++n) acc[n] = make_float4(0.f, 0.f, 0.f, 0.f);

    for (int t = 0; t < ns; ++t) {
        const float* bt = base + (size_t)t * D_PROJ;
        #pragma unroll
        for (int n = 0; n < 8; ++n) {
            float4 v = *(const float4*)(bt + tid * 4 + n * 1024);
            acc[n].x += v.x; acc[n].y += v.y; acc[n].z += v.z; acc[n].w += v.w;
        }
    }

    float s = 0.0f;
    #pragma unroll
    for (int n = 0; n < 8; ++n)
        s += fabsf(acc[n].x) + fabsf(acc[n].y) + fabsf(acc[n].z) + fabsf(acc[n].w);
    #pragma unroll
    for (int off = 32; off > 0; off >>= 1) s += __shfl_down(s, off, 64);
    __shared__ float red[4];
    if ((tid & 63) == 0) red[tid >> 6] = s;
    __syncthreads();
    float total = red[0] + red[1] + red[2] + red[3];
    float inv   = 1.0f / fmaxf(sqrtf(total + (float)D_PROJ * 1e-8f), 1e-12f);

    float* ob = out + (size_t)b * D_PROJ;
    #pragma unroll
    for (int n = 0; n < 8; ++n) {
        const int k = tid * 4 + n * 1024;
        float4 a = acc[n];
        float4 r;
        r.x = ssqrt_scale(a.x, inv);
        r.y = ssqrt_scale(a.y, inv);
        r.z = ssqrt_scale(a.z, inv);
        r.w = ssqrt_scale(a.w, inv);
        *(float4*)(ob + k) = r;
    }
}

__global__ __launch_bounds__(256) void finalize_inplace(float* __restrict__ out)
{
    const int b = blockIdx.x;
    float* p = out + (size_t)b * D_PROJ;
    const int tid = threadIdx.x;

    float s = 0.0f;
    for (int d = tid; d < D_PROJ; d += 256) s += fabsf(p[d]);
    #pragma unroll
    for (int off = 32; off > 0; off >>= 1) s += __shfl_down(s, off, 64);
    __shared__ float red[4];
    if ((tid & 63) == 0) red[tid >> 6] = s;
    __syncthreads();
    float total = red[0] + red[1] + red[2] + red[3];
    float inv   = 1.0f / fmaxf(sqrtf(total + (float)D_PROJ * 1e-8f), 1e-12f);

    for (int d = tid; d < D_PROJ; d += 256) {
        float v = p[d];
        float r = sqrtf(fabsf(v) + 1e-8f) * inv;
        p[d] = (v > 0.0f) ? r : ((v < 0.0f) ? -r : 0.0f);
    }
}

// ---------------------------------------------------------------------------
extern "C" void kernel_launch(void* const* d_in, const int* in_sizes, int n_in,
                              void* d_out, int out_size, void* d_ws, size_t ws_size,
                              hipStream_t stream)
{
    const float* x  = (const float*)d_in[0];   // [32, 512, 14, 14]
    const float* S1 = (const float*)d_in[1];   // [512, 8192]
    const float* S2 = (const float*)d_in[2];   // [512, 8192]
    float* out = (float*)d_out;                // [32, 8192]

    char* ws = (char*)d_ws;
    int*   h1 = (int*)(ws);
    float* s1 = (float*)(ws + 2048);
    int*   h2 = (int*)(ws + 4096);
    float* s2 = (float*)(ws + 6144);

    const size_t XT_BYTES   = (size_t)NBATCH * P_SP * C_IN * sizeof(float);   // 12.85 MB
    const size_t PART_BYTES = (size_t)NBATCH * NTILE * D_PROJ * sizeof(float);// 16.8 MB
    float* xT      = (float*)(ws + 8192);
    float* partial = (float*)(ws + 8192 + XT_BYTES);

    extract_sketch<<<1024, 256, 0, stream>>>(S1, S2, h1, s1, h2, s2);

    if (ws_size >= 8192 + XT_BYTES + PART_BYTES) {
        transpose_x<<<dim3(4, 8, NBATCH), 256, 0, stream>>>(x, xT);
        gram_scatter<<<512, 256, 0, stream>>>(xT, h1, s1, h2, s2, partial, 1);
        finalize_partial<<<NBATCH, 256, 0, stream>>>(partial, out, NTILE);
    } else if (ws_size >= 8192 + XT_BYTES) {
        hipMemsetAsync(d_out, 0, (size_t)out_size * sizeof(float), stream);
        transpose_x<<<dim3(4, 8, NBATCH), 256, 0, stream>>>(x, xT);
        gram_scatter<<<512, 256, 0, stream>>>(xT, h1, s1, h2, s2, out, 0);
        finalize_inplace<<<NBATCH, 256, 0, stream>>>(out);
    } else {
        hipMemsetAsync(d_out, 0, (size_t)out_size * sizeof(float), stream);
        gram_scatter_legacy<<<512, 256, 0, stream>>>(x, h1, s1, h2, s2, out);
        finalize_inplace<<<NBATCH, 256, 0, stream>>>(out);
    }
}